// Round 4
// baseline (667.325 us; speedup 1.0000x reference)
//
#include <hip/hip_runtime.h>

// ---------------------------------------------------------------------------
// MultiOmicsGenerator: N=4 nodes, LAT=256, HID=512, omics dims
// {ge:20000, meth:200000, mirna:2000, cnv:25000}. Inputs are fp32 (verified
// R3: dtype detector took fp32 branch); bf16 fallback path retained.
//
// Fully-connected graph + self loops => GCN rows all equal mean of
// transformed rows:
//   v = mean(L); a = relu(v@Wg1); x = relu(a@Wg2)
//   h[t] = relu(BN1(x @ W1[t] + b1[t]))          (t = 0..3)
//   out_k = BN2(h[k] @ W2_k + b2_k)              (k = 0..3)
//
// R4: k_omics restructured for occupancy: 256-thread blocks, 4 cols/thread
// (float4/row), K-split 2-way into fp32 partials (ws), BN epilogue kernel.
// 484 waves -> 1944 waves (7.6/CU); in-flight ~16 MB >> 2.4 MB lat-BW prod.
// ---------------------------------------------------------------------------

#define EPS 1e-3f

typedef unsigned short u16;
typedef unsigned int   u32;

__device__ __forceinline__ float b2f(u16 u) {
    union { u32 i; float f; } v; v.i = ((u32)u) << 16; return v.f;
}
__device__ __forceinline__ float lo16(u32 u) {
    union { u32 i; float f; } v; v.i = u << 16; return v.f;
}
__device__ __forceinline__ float hi16(u32 u) {
    union { u32 i; float f; } v; v.i = u & 0xffff0000u; return v.f;
}
__device__ __forceinline__ u16 f2b(float f) {
    union { float f; u32 i; } v; v.f = f;
    u32 r = v.i + 0x7fffu + ((v.i >> 16) & 1u);   // round-nearest-even
    return (u16)(r >> 16);
}
__device__ __forceinline__ float ldin(const void* p, int i, int bf) {
    return bf ? b2f(((const u16*)p)[i]) : ((const float*)p)[i];
}

// K0: dtype detector. 1 block x 64. flag: 0 = fp32, 1 = bf16.
__global__ void k_detect(const void* __restrict__ L, int* __restrict__ flag) {
    const float* f = (const float*)L;
    int t = threadIdx.x;
    float mx = 0.f;
    for (int i = t; i < 256; i += 64) {
        float v = fabsf(f[i]);
        if (!(v < 1e30f)) v = 1e30f;      // catches Inf and NaN
        mx = fmaxf(mx, v);
    }
    for (int o = 32; o; o >>= 1) mx = fmaxf(mx, __shfl_down(mx, o));
    if (t == 0) flag[0] = (mx < 1e6f) ? 0 : 1;
}

// K1: a = relu(mean(L) @ Wg1).  grid=4 x 256.
__global__ void k_stage1(const void* __restrict__ L,
                         const void* __restrict__ Wg1,
                         const int* __restrict__ flagp,
                         float* __restrict__ a_out) {
    int bf = flagp[0];
    __shared__ float v[256];
    __shared__ float part[4][64];
    int t = threadIdx.x;
    v[t] = 0.25f * (ldin(L, t, bf) + ldin(L, 256 + t, bf) +
                    ldin(L, 512 + t, bf) + ldin(L, 768 + t, bf));
    __syncthreads();
    int rg = t >> 6, cl = t & 63;
    int col = blockIdx.x * 64 + cl;
    int r0 = rg * 64;
    float s = 0.f;
#pragma unroll 8
    for (int r = r0; r < r0 + 64; ++r) s = fmaf(v[r], ldin(Wg1, r * 256 + col, bf), s);
    part[rg][cl] = s;
    __syncthreads();
    if (t < 64) {
        float sum = part[0][t] + part[1][t] + part[2][t] + part[3][t];
        a_out[blockIdx.x * 64 + t] = fmaxf(sum, 0.f);
    }
}

// K2: x = relu(a @ Wg2).  grid=4 x 256.
__global__ void k_stage2(const float* __restrict__ a_in,
                         const void* __restrict__ Wg2,
                         const int* __restrict__ flagp,
                         float* __restrict__ x_out) {
    int bf = flagp[0];
    __shared__ float v[256];
    __shared__ float part[4][64];
    int t = threadIdx.x;
    v[t] = a_in[t];
    __syncthreads();
    int rg = t >> 6, cl = t & 63;
    int col = blockIdx.x * 64 + cl;
    int r0 = rg * 64;
    float s = 0.f;
#pragma unroll 8
    for (int r = r0; r < r0 + 64; ++r) s = fmaf(v[r], ldin(Wg2, r * 256 + col, bf), s);
    part[rg][cl] = s;
    __syncthreads();
    if (t < 64) {
        float sum = part[0][t] + part[1][t] + part[2][t] + part[3][t];
        x_out[blockIdx.x * 64 + t] = fmaxf(sum, 0.f);
    }
}

// K3: h[node][col] = relu(BN1(x @ W1[node] + b1)).  grid=32 x 256.
__global__ void k_stage3(const float* __restrict__ x_in,
                         const void* __restrict__ W1,
                         const void* __restrict__ b1,
                         const void* __restrict__ g1,
                         const void* __restrict__ be1,
                         const void* __restrict__ m1,
                         const void* __restrict__ v1,
                         const int* __restrict__ flagp,
                         float* __restrict__ h_out) {
    int bf = flagp[0];
    __shared__ float x[256];
    __shared__ float part[4][64];
    int t = threadIdx.x;
    x[t] = x_in[t];
    __syncthreads();
    int rg = t >> 6, cl = t & 63;
    int o = blockIdx.x * 64 + cl;
    int node = o >> 9, col = o & 511;
    int wbase = node * (256 * 512);
    int r0 = rg * 64;
    float s = 0.f;
#pragma unroll 8
    for (int r = r0; r < r0 + 64; ++r) s = fmaf(x[r], ldin(W1, wbase + r * 512 + col, bf), s);
    part[rg][cl] = s;
    __syncthreads();
    if (t < 64) {
        int oo = blockIdx.x * 64 + t;      // == node*512 + col
        float y = part[0][t] + part[1][t] + part[2][t] + part[3][t] + ldin(b1, oo, bf);
        float bn = ldin(g1, oo, bf) * (y - ldin(m1, oo, bf)) * rsqrtf(ldin(v1, oo, bf) + EPS)
                 + ldin(be1, oo, bf);
        h_out[oo] = fmaxf(bn, 0.f);
    }
}

// K4: partial[half][ooff+j..j+4) = sum_{r in half} h[k][r] * W2_k[r][j..j+4).
// grid = 486 x 256: b%243 selects col-block, b/243 selects K-half.
// Col-blocks: ge [0,20), meth [20,216), mirna [216,218), cnv [218,243);
// each covers 1024 cols (256 threads x 4 cols).
__global__ __launch_bounds__(256) void k_omics(
    const void* __restrict__ W2g, const void* __restrict__ W2m,
    const void* __restrict__ W2r, const void* __restrict__ W2c,
    const float* __restrict__ h_all, const int* __restrict__ flagp,
    float* __restrict__ partial) {

    int bf = flagp[0];
    int b = blockIdx.x;
    int cb = b % 243, half = b / 243;

    const void* W2;
    int k, lb, dim, ooff;
    if (cb < 20)       { k = 0; lb = cb;       dim = 20000;  ooff = 0;      W2 = W2g; }
    else if (cb < 216) { k = 1; lb = cb - 20;  dim = 200000; ooff = 20000;  W2 = W2m; }
    else if (cb < 218) { k = 2; lb = cb - 216; dim = 2000;   ooff = 220000; W2 = W2r; }
    else               { k = 3; lb = cb - 218; dim = 25000;  ooff = 222000; W2 = W2c; }

    __shared__ float h[256];
    int t = threadIdx.x;
    h[t] = h_all[k * 512 + half * 256 + t];
    __syncthreads();

    int j = lb * 1024 + t * 4;
    if (j >= dim) return;

    float a0 = 0.f, a1 = 0.f, a2 = 0.f, a3 = 0.f;

    if (bf) {
        const u16* W = (const u16*)W2 + (size_t)half * 256 * dim + j;
#pragma unroll 8
        for (int r = 0; r < 256; ++r) {
            const u16* p = W + (size_t)r * dim;    // 4B aligned (dim, j even)
            u32 w0 = *(const u32*)(p + 0);
            u32 w1 = *(const u32*)(p + 2);
            float hr = h[r];
            a0 = fmaf(hr, lo16(w0), a0); a1 = fmaf(hr, hi16(w0), a1);
            a2 = fmaf(hr, lo16(w1), a2); a3 = fmaf(hr, hi16(w1), a3);
        }
    } else {
        const float* W = (const float*)W2 + (size_t)half * 256 * dim + j;
#pragma unroll 8
        for (int r = 0; r < 256; ++r) {
            float4 w = *(const float4*)(W + (size_t)r * dim);  // 16B aligned (dim%4==0, j%4==0)
            float hr = h[r];
            a0 = fmaf(hr, w.x, a0); a1 = fmaf(hr, w.y, a1);
            a2 = fmaf(hr, w.z, a2); a3 = fmaf(hr, w.w, a3);
        }
    }

    float4 o = {a0, a1, a2, a3};
    *(float4*)(partial + (size_t)half * 247000 + ooff + j) = o;   // 16B aligned
}

// K5: out[j..j+4) = BN2(part0 + part1 + b2).  grid = 242 x 256.
// Omic boundaries (20000, 220000, 222000) are %4==0 -> no thread straddles.
__global__ __launch_bounds__(256) void k_bn(
    const void* __restrict__ b2g, const void* __restrict__ g2g, const void* __restrict__ be2g,
    const void* __restrict__ m2g, const void* __restrict__ v2g,
    const void* __restrict__ b2m, const void* __restrict__ g2m, const void* __restrict__ be2m,
    const void* __restrict__ m2m, const void* __restrict__ v2m,
    const void* __restrict__ b2r, const void* __restrict__ g2r, const void* __restrict__ be2r,
    const void* __restrict__ m2r, const void* __restrict__ v2r,
    const void* __restrict__ b2c, const void* __restrict__ g2c, const void* __restrict__ be2c,
    const void* __restrict__ m2c, const void* __restrict__ v2c,
    const float* __restrict__ partial, const int* __restrict__ flagp,
    void* __restrict__ outv) {

    int bf = flagp[0];
    int j = (blockIdx.x * 256 + threadIdx.x) * 4;
    if (j >= 247000) return;

    const void *b2, *g2, *be2, *m2, *v2;
    int jj;
    if (j < 20000)       { jj = j;          b2 = b2g; g2 = g2g; be2 = be2g; m2 = m2g; v2 = v2g; }
    else if (j < 220000) { jj = j - 20000;  b2 = b2m; g2 = g2m; be2 = be2m; m2 = m2m; v2 = v2m; }
    else if (j < 222000) { jj = j - 220000; b2 = b2r; g2 = g2r; be2 = be2r; m2 = m2r; v2 = v2r; }
    else                 { jj = j - 222000; b2 = b2c; g2 = g2c; be2 = be2c; m2 = m2c; v2 = v2c; }

    float4 p0 = *(const float4*)(partial + j);
    float4 p1 = *(const float4*)(partial + 247000 + j);
    float acc[4] = {p0.x + p1.x, p0.y + p1.y, p0.z + p1.z, p0.w + p1.w};

    float res[4];
    if (bf) {
#pragma unroll
        for (int i = 0; i < 4; ++i) {
            float y = acc[i] + b2f(((const u16*)b2)[jj + i]);
            res[i] = b2f(((const u16*)g2)[jj + i]) * (y - b2f(((const u16*)m2)[jj + i])) *
                     rsqrtf(b2f(((const u16*)v2)[jj + i]) + EPS) +
                     b2f(((const u16*)be2)[jj + i]);
        }
        u16* out = (u16*)outv;
        u32* po = (u32*)(out + j);                 // 4B aligned
        po[0] = (u32)f2b(res[0]) | ((u32)f2b(res[1]) << 16);
        po[1] = (u32)f2b(res[2]) | ((u32)f2b(res[3]) << 16);
    } else {
        float4 bw  = *(const float4*)((const float*)b2  + jj);   // 16B aligned (jj%4==0)
        float4 gw  = *(const float4*)((const float*)g2  + jj);
        float4 mw  = *(const float4*)((const float*)m2  + jj);
        float4 vw  = *(const float4*)((const float*)v2  + jj);
        float4 bew = *(const float4*)((const float*)be2 + jj);
        res[0] = gw.x * (acc[0] + bw.x - mw.x) * rsqrtf(vw.x + EPS) + bew.x;
        res[1] = gw.y * (acc[1] + bw.y - mw.y) * rsqrtf(vw.y + EPS) + bew.y;
        res[2] = gw.z * (acc[2] + bw.z - mw.z) * rsqrtf(vw.z + EPS) + bew.z;
        res[3] = gw.w * (acc[3] + bw.w - mw.w) * rsqrtf(vw.w + EPS) + bew.w;
        float4 o = {res[0], res[1], res[2], res[3]};
        *(float4*)((float*)outv + j) = o;          // 16B aligned
    }
}

extern "C" void kernel_launch(void* const* d_in, const int* in_sizes, int n_in,
                              void* d_out, int out_size, void* d_ws, size_t ws_size,
                              hipStream_t stream) {
    const void* L   = d_in[0];
    const void* Wg1 = d_in[1];
    const void* Wg2 = d_in[2];
    const void* W1  = d_in[3];
    const void* b1  = d_in[4];
    const void* g1  = d_in[5];
    const void* be1 = d_in[6];
    const void* m1  = d_in[7];
    const void* v1  = d_in[8];

    const void* P[24];
    for (int i = 0; i < 24; ++i) P[i] = d_in[9 + i];
    // P layout per omic k: [6k]=W2, [6k+1]=b2, [6k+2]=g2, [6k+3]=be2, [6k+4]=m2, [6k+5]=v2

    float* ws = (float*)d_ws;     // [0,256) a ; [256,512) x ; [512,2560) h
    int* flag = (int*)(ws + 2560);
    float* partial = ws + 2576;   // 2 x 247000 floats, 16B-aligned base

    k_detect<<<dim3(1),  dim3(64),  0, stream>>>(L, flag);
    k_stage1<<<dim3(4),  dim3(256), 0, stream>>>(L, Wg1, flag, ws);
    k_stage2<<<dim3(4),  dim3(256), 0, stream>>>(ws, Wg2, flag, ws + 256);
    k_stage3<<<dim3(32), dim3(256), 0, stream>>>(ws + 256, W1, b1, g1, be1, m1, v1, flag, ws + 512);
    k_omics <<<dim3(486), dim3(256), 0, stream>>>(P[0], P[6], P[12], P[18],
                                                  ws + 512, flag, partial);
    k_bn    <<<dim3(242), dim3(256), 0, stream>>>(
        P[1],  P[2],  P[3],  P[4],  P[5],
        P[7],  P[8],  P[9],  P[10], P[11],
        P[13], P[14], P[15], P[16], P[17],
        P[19], P[20], P[21], P[22], P[23],
        partial, flag, d_out);
}